// Round 14
// baseline (634.082 us; speedup 1.0000x reference)
//
#include <hip/hip_runtime.h>
#include <cfloat>

#define BB 8
#define NN 1024
#define CC 256
#define KK 4096
#define SN 11
#define BNC (BB*NN*CC)
#define RMAX 8192

typedef __attribute__((ext_vector_type(8))) _Float16 half8;
typedef __attribute__((ext_vector_type(4))) float f32x4;

__device__ __forceinline__ void split2(float v, ushort& h, ushort& l) {
    union { _Float16 f; ushort u; } a, b;
    a.f = (_Float16)v;
    b.f = (_Float16)(v - (float)a.f);
    h = a.u; l = b.u;
}

// ---------------------------------------------------------------------------
// merged: blocks 0-255 embed (pw read transposed directly); 256-767 init_pool16
__global__ __launch_bounds__(256) void embed_prep(
    const float* __restrict__ base, const float* __restrict__ pw,
    const float* __restrict__ pb, const float* __restrict__ f,
    float* __restrict__ emb, ushort* __restrict__ eh, ushort* __restrict__ el,
    float* __restrict__ esq, float* __restrict__ p16) {
    int blk = blockIdx.x;
    int t = threadIdx.x;
    if (blk >= 256) {
        int bb = blk - 256;
        int c4 = t & 63;
        const float4* src = (const float4*)(f + (size_t)bb * 16 * CC) + c4;
        float4 s = make_float4(0.f, 0.f, 0.f, 0.f);
#pragma unroll
        for (int j = 0; j < 16; ++j) {
            float4 v = src[(size_t)j * 64];
            s.x += v.x; s.y += v.y; s.z += v.z; s.w += v.w;
        }
        ((float4*)(p16 + (size_t)bb * CC))[c4] = s;
        return;
    }
    __shared__ float bs[16][CC];
    __shared__ float wpart[16][4];
    int k0 = blk * 16;
    int w = t >> 6, lane = t & 63;
    for (int i = t; i < 16 * CC; i += 256) bs[i >> 8][i & 255] = base[k0 * CC + i];
    __syncthreads();
    float acc[16];
#pragma unroll
    for (int m = 0; m < 16; ++m) acc[m] = 0.f;
    for (int j = 0; j < CC; ++j) {
        float wv = pw[t * CC + j];
#pragma unroll
        for (int m = 0; m < 16; ++m) acc[m] += bs[m][j] * wv;
    }
    float bias = pb[t];
#pragma unroll
    for (int m = 0; m < 16; ++m) {
        float v = acc[m] + bias;
        int o = (k0 + m) * CC + t;
        emb[o] = v;
        ushort h, l;
        split2(64.f * v, h, l);
        eh[o] = h; el[o] = l;
        float sq = v * v;
#pragma unroll
        for (int d = 1; d < 64; d <<= 1) sq += __shfl_xor(sq, d);
        if (lane == 0) wpart[m][w] = sq;
    }
    __syncthreads();
    if (t < 16) esq[k0 + t] = wpart[t][0] + wpart[t][1] + wpart[t][2] + wpart[t][3];
}

// ---------------------------------------------------------------------------
// exact f32 distance+argmin for small scales (R <= 512), with fused pooling.
// srow = row stride of src in 256-float rows (64 for p16 pyramid, pn for qf).
// pval/pidx passed pre-offset per scale (persistent region, scales 0..6).
__global__ __launch_bounds__(256, 4) void dist_small(
    const float* __restrict__ src, const float* __restrict__ emb,
    const float* __restrict__ esq, int R, int g16, int pn, int srow, float inv,
    float* __restrict__ pval, int* __restrict__ pidx) {
    __shared__ float qs[32][CC];
    __shared__ float es[64][33];
    int t = threadIdx.x;
    int ws = t >> 6, j = t & 63;
    int k0 = blockIdx.x * 64;
    int r0c = blockIdx.y * 32;
    {
        int row = t >> 3;
        int f4b = (t & 7) * 8;
        int gr = r0c + row;
        float4 a4[8];
#pragma unroll
        for (int ii = 0; ii < 8; ++ii) a4[ii] = make_float4(0.f, 0.f, 0.f, 0.f);
        if (gr < R) {
            int b = gr / pn, p = gr - b * pn;
            const float4* sp = (const float4*)(src + ((size_t)b * srow + (size_t)p * g16) * CC) + f4b;
            for (int i = 0; i < g16; ++i) {
#pragma unroll
                for (int ii = 0; ii < 8; ++ii) {
                    float4 v = sp[ii];
                    a4[ii].x += v.x; a4[ii].y += v.y; a4[ii].z += v.z; a4[ii].w += v.w;
                }
                sp += 64;
            }
        }
#pragma unroll
        for (int ii = 0; ii < 8; ++ii) {
            a4[ii].x *= inv; a4[ii].y *= inv; a4[ii].z *= inv; a4[ii].w *= inv;
            *(float4*)&qs[row][(f4b + ii) * 4] = a4[ii];
        }
    }
    float acc[8];
#pragma unroll
    for (int ri = 0; ri < 8; ++ri) acc[ri] = 0.f;
    for (int ck = 0; ck < 8; ++ck) {
        __syncthreads();
        {
            int code = t >> 2, cb = (t & 3) * 8;
            float4 v0 = *(const float4*)&emb[(size_t)(k0 + code) * CC + ck * 32 + cb];
            float4 v1 = *(const float4*)&emb[(size_t)(k0 + code) * CC + ck * 32 + cb + 4];
            es[code][cb + 0] = v0.x; es[code][cb + 1] = v0.y;
            es[code][cb + 2] = v0.z; es[code][cb + 3] = v0.w;
            es[code][cb + 4] = v1.x; es[code][cb + 5] = v1.y;
            es[code][cb + 6] = v1.z; es[code][cb + 7] = v1.w;
        }
        __syncthreads();
        for (int c = 0; c < 32; ++c) {
            float ev = es[j][c];
#pragma unroll
            for (int ri = 0; ri < 8; ++ri)
                acc[ri] += qs[ws + 4 * ri][ck * 32 + c] * ev;
        }
    }
    float esv = esq[k0 + j];
#pragma unroll
    for (int ri = 0; ri < 8; ++ri) {
        int r = r0c + ws + 4 * ri;
        if (r >= R) continue;
        float v = esv - 2.f * acc[ri];
        int bi = k0 + j;
#pragma unroll
        for (int d = 1; d < 64; d <<= 1) {
            float ov = __shfl_xor(v, d);
            int oi = __shfl_xor(bi, d);
            if (ov < v || (ov == v && oi < bi)) { v = ov; bi = oi; }
        }
        if (j == 0) {
            pval[(size_t)r * 64 + blockIdx.x] = v;
            pidx[(size_t)r * 64 + blockIdx.x] = bi;
        }
    }
}

// ---------------------------------------------------------------------------
// pooled-domain q production for scales 1..6:
// q[r=(b,p)] = pool(f)[r] - sum_{j<=sc} pool(h_j)[r], h_j piecewise-linear.
// Reads PERSISTENT partials: scale jj rows live at rowoff(jj)=BB*(2^jj-1).
__global__ __launch_bounds__(256) void combineQ(
    const float* __restrict__ pvS, const int* __restrict__ piS,
    const float* __restrict__ p16, const float* __restrict__ emb,
    float* __restrict__ qf, int sc, int pn_next) {
    int r = blockIdx.x;
    int b = r / pn_next, p = r - b * pn_next;
    int g = 1024 / pn_next;     // >= 16
    int g16 = 64 / pn_next;     // >= 1
    int t = threadIdx.x, w = t >> 6, lane = t & 63;
    __shared__ int sidx[64];
    int nitems = (2 << sc) - 1;  // sum of pn_j for j<=sc
    for (int item = w; item < nitems; item += 4) {
        int jj = 31 - __builtin_clz(item + 1);
        int q = item + 1 - (1 << jj);
        // persistent row: rowoff(jj) + b*2^jj + q
        size_t rowg = ((size_t)BB * ((1u << jj) - 1) + (size_t)b * (1 << jj) + q) * 64;
        float v = pvS[rowg + lane];
        int ii = piS[rowg + lane];
#pragma unroll
        for (int d = 1; d < 64; d <<= 1) {
            float ov = __shfl_xor(v, d);
            int oi = __shfl_xor(ii, d);
            if (ov < v || (ov == v && oi < ii)) { v = ov; ii = oi; }
        }
        if (lane == 0) sidx[item] = ii;
    }
    __syncthreads();
    float base = 0.f;
    for (int i = 0; i < g16; ++i)
        base += p16[((size_t)b * 64 + (size_t)p * g16 + i) * CC + t];
    float hsum = 0.f;
    for (int j = 0; j <= sc; ++j) {
        int pnj = 1 << j, off = pnj - 1;
        int curi0 = -1, curi1 = 0;
        float c0 = 0.f, c1 = 0.f;
        for (int n = p * g; n < p * g + g; ++n) {
            float s = (n + 0.5f) * (float)pnj * (1.f / 1024.f) - 0.5f;
            if (s < 0.f) s = 0.f;
            int i0 = (int)s;
            float wq = s - (float)i0;
            if (i0 != curi0) {
                if (curi0 >= 0)
                    hsum += c0 * emb[(size_t)sidx[off + curi0] * CC + t]
                          + c1 * emb[(size_t)sidx[off + curi1] * CC + t];
                curi0 = i0;
                curi1 = min(i0 + 1, pnj - 1);
                c0 = 0.f; c1 = 0.f;
            }
            c0 += 1.f - wq;
            c1 += wq;
        }
        hsum += c0 * emb[(size_t)sidx[off + curi0] * CC + t]
              + c1 * emb[(size_t)sidx[off + curi1] * CC + t];
    }
    qf[(size_t)r * CC + t] = base * (1.f / (16.f * (float)g16)) - hsum * (1.f / (float)g);
}

// ---------------------------------------------------------------------------
// one full-resolution sweep replaying scales 0..6: per-scale losses, resid_7,
// and scale-7 (pn=128) q-splits. grid 512 = (b, n16), 256 threads.
// Reads PERSISTENT partials with rowoff(j)=BB*(2^j-1).
__global__ __launch_bounds__(256) void bigpass(
    const float* __restrict__ f, const float* __restrict__ emb,
    const float* __restrict__ pvS, const int* __restrict__ piS,
    float* __restrict__ resid, float* __restrict__ parts,
    ushort* __restrict__ qh, ushort* __restrict__ ql) {
    int blk = blockIdx.x;
    int b = blk >> 6, n16 = blk & 63;
    int t = threadIdx.x;
    int w = t >> 6, lane = t & 63;
    int n0 = n16 * 16;
    __shared__ int sidx7[7][4];
    __shared__ float4 rlds[16][64];
    __shared__ float wred7[7][4];
    int combo = 0;
    for (int j = 0; j < 7; ++j) {
        int pnj = 1 << j;
        int rowoff = BB * (pnj - 1);
        float sl = (n0 + 0.5f) * (float)pnj * (1.f / 1024.f) - 0.5f;
        if (sl < 0.f) sl = 0.f;
        int rlo = (int)sl;
        float sh = (n0 + 15.5f) * (float)pnj * (1.f / 1024.f) - 0.5f;
        if (sh < 0.f) sh = 0.f;
        int rhi = min((int)sh + 1, pnj - 1);
        for (int ri = 0; ri <= rhi - rlo; ++ri, ++combo) {
            if ((combo & 3) == w) {
                size_t rowg = (size_t)(rowoff + b * pnj + rlo + ri) * 64;
                float v = pvS[rowg + lane];
                int ii = piS[rowg + lane];
#pragma unroll
                for (int d = 1; d < 64; d <<= 1) {
                    float ov = __shfl_xor(v, d);
                    int oi = __shfl_xor(ii, d);
                    if (ov < v || (ov == v && oi < ii)) { v = ov; ii = oi; }
                }
                if (lane == 0) sidx7[j][ri] = ii;
            }
        }
    }
    __syncthreads();
    int nsub = t >> 6;
    int c4 = t & 63;
    float sq[7];
#pragma unroll
    for (int j = 0; j < 7; ++j) sq[j] = 0.f;
#pragma unroll
    for (int jj = 0; jj < 4; ++jj) {
        int j16 = nsub + 4 * jj;
        int n = n0 + j16;
        size_t o4 = ((size_t)b * NN + n) * 64 + c4;
        float4 r = ((const float4*)f)[o4];
#pragma unroll
        for (int j = 0; j < 7; ++j) {
            int pnj = 1 << j;
            float s = (n + 0.5f) * (float)pnj * (1.f / 1024.f) - 0.5f;
            if (s < 0.f) s = 0.f;
            int i0 = (int)s;
            float wgt = s - (float)i0;
            int i1 = min(i0 + 1, pnj - 1);
            float sl = (n0 + 0.5f) * (float)pnj * (1.f / 1024.f) - 0.5f;
            if (sl < 0.f) sl = 0.f;
            int rlo = (int)sl;
            int k0 = sidx7[j][i0 - rlo];
            int k1 = sidx7[j][i1 - rlo];
            float4 e0 = ((const float4*)(emb + (size_t)k0 * CC))[c4];
            float4 e1 = ((const float4*)(emb + (size_t)k1 * CC))[c4];
            float wm = 1.f - wgt;
            r.x -= wm * e0.x + wgt * e1.x;
            r.y -= wm * e0.y + wgt * e1.y;
            r.z -= wm * e0.z + wgt * e1.z;
            r.w -= wm * e0.w + wgt * e1.w;
            sq[j] += r.x * r.x + r.y * r.y + r.z * r.z + r.w * r.w;
        }
        ((float4*)resid)[o4] = r;
        rlds[j16][c4] = r;
    }
#pragma unroll
    for (int j = 0; j < 7; ++j) {
        float s = sq[j];
        for (int off = 32; off > 0; off >>= 1) s += __shfl_down(s, off);
        if (lane == 0) wred7[j][w] = s;
    }
    __syncthreads();
    if (t < 7) parts[(size_t)t * 512 + blk] =
        wred7[t][0] + wred7[t][1] + wred7[t][2] + wred7[t][3];
    const float* rl = (const float*)rlds;
    float pr = 0.f;
    for (int j16 = 0; j16 < 16; ++j16) {
        pr += rl[j16 * CC + t];
        if ((j16 & 7) == 7) {
            float mean = pr * 0.125f;
            ushort H, L;
            split2(64.f * mean, H, L);
            size_t r = (size_t)b * 128 + (size_t)((n0 + j16) >> 3);
            qh[r * CC + t] = H;
            ql[r * CC + t] = L;
            pr = 0.f;
        }
    }
}

// ---------------------------------------------------------------------------
// MFMA distance, pn >= 128 (2-phase-ceiling version, unchanged).
__global__ __launch_bounds__(256, 2) void dist_mfma(
    const ushort* __restrict__ qh, const ushort* __restrict__ ql,
    const ushort* __restrict__ eh, const ushort* __restrict__ el,
    const float* __restrict__ esq,
    float* __restrict__ pval, int* __restrict__ pidx) {
    __shared__ ushort tiles[4096 * 8];  // 64 KB
    __shared__ float wv[2][128];
    __shared__ int wi[2][128];
    int t = threadIdx.x;
    int w = t >> 6, lane = t & 63;
    int l15 = lane & 15, hi = lane >> 4;
    int wr = w >> 1, wc = w & 1;
    int r0 = blockIdx.x * 128;
    int kb = blockIdx.y;
    int k0 = kb * 128;

    f32x4 acc[4][4];
#pragma unroll
    for (int mi = 0; mi < 4; ++mi)
#pragma unroll
        for (int ni = 0; ni < 4; ++ni) acc[mi][ni] = (f32x4){0.f, 0.f, 0.f, 0.f};

    for (int ck = 0; ck < 4; ++ck) {
        __syncthreads();
#pragma unroll
        for (int it = 0; it < 16; ++it) {
            int s = it * 256 + t;
            const ushort* g;
            if (s < 2048) {
                int a = s >> 10;
                int rem = s & 1023;
                int row = rem >> 3, sr = rem & 7;
                int c = (ck << 6) + ((sr ^ (row & 7)) << 3);
                g = (a ? ql : qh) + (size_t)(r0 + row) * CC + c;
            } else {
                int s2 = s - 2048;
                int b = s2 >> 10;
                int rem = s2 & 1023;
                int kcol = rem >> 3, sr = rem & 7;
                int c = (ck << 6) + ((sr ^ (kcol & 7)) << 3);
                g = (b ? el : eh) + (size_t)(k0 + kcol) * CC + c;
            }
            ushort* lb = &tiles[(size_t)(it * 256 + (w << 6)) * 8];
            __builtin_amdgcn_global_load_lds(
                (const __attribute__((address_space(1))) unsigned int*)g,
                (__attribute__((address_space(3))) unsigned int*)lb, 16, 0, 0);
        }
        __syncthreads();

#pragma unroll
        for (int kk = 0; kk < 2; ++kk) {
            int cs = (kk << 2) + hi;
            half8 bf0[4], bf1[4], af[4];
#pragma unroll
            for (int ni = 0; ni < 4; ++ni) {
                int kcol = (wc << 6) + (ni << 4) + l15;
                int sb = 2048 + (kcol << 3) + (cs ^ (kcol & 7));
                bf0[ni] = *(const half8*)&tiles[sb * 8];
                bf1[ni] = *(const half8*)&tiles[(sb + 1024) * 8];
            }
#pragma unroll
            for (int mi = 0; mi < 4; ++mi) {
                int row = (wr << 6) + (mi << 4) + l15;
                af[mi] = *(const half8*)&tiles[((row << 3) + (cs ^ (row & 7))) * 8];
            }
#pragma unroll
            for (int mi = 0; mi < 4; ++mi)
#pragma unroll
                for (int ni = 0; ni < 4; ++ni)
                    acc[mi][ni] = __builtin_amdgcn_mfma_f32_16x16x32_f16(af[mi], bf0[ni], acc[mi][ni], 0, 0, 0);
#pragma unroll
            for (int mi = 0; mi < 4; ++mi)
#pragma unroll
                for (int ni = 0; ni < 4; ++ni)
                    acc[mi][ni] = __builtin_amdgcn_mfma_f32_16x16x32_f16(af[mi], bf1[ni], acc[mi][ni], 0, 0, 0);
#pragma unroll
            for (int mi = 0; mi < 4; ++mi) {
                int row = (wr << 6) + (mi << 4) + l15;
                af[mi] = *(const half8*)&tiles[(1024 + (row << 3) + (cs ^ (row & 7))) * 8];
            }
#pragma unroll
            for (int mi = 0; mi < 4; ++mi)
#pragma unroll
                for (int ni = 0; ni < 4; ++ni)
                    acc[mi][ni] = __builtin_amdgcn_mfma_f32_16x16x32_f16(af[mi], bf0[ni], acc[mi][ni], 0, 0, 0);
        }
    }

    int cbase = k0 + (wc << 6) + l15;
    float es4[4];
#pragma unroll
    for (int ni = 0; ni < 4; ++ni) es4[ni] = 4096.f * esq[cbase + ni * 16];
#pragma unroll
    for (int mi = 0; mi < 4; ++mi) {
#pragma unroll
        for (int reg = 0; reg < 4; ++reg) {
            float v = es4[0] - 2.f * acc[mi][0][reg];
            int i = cbase;
#pragma unroll
            for (int ni = 1; ni < 4; ++ni) {
                float v1 = es4[ni] - 2.f * acc[mi][ni][reg];
                if (v1 < v) { v = v1; i = cbase + ni * 16; }
            }
#pragma unroll
            for (int d = 1; d < 16; d <<= 1) {
                float ov = __shfl_xor(v, d);
                int oi = __shfl_xor(i, d);
                if (ov < v || (ov == v && oi < i)) { v = ov; i = oi; }
            }
            if (l15 == 0) {
                int row = (wr << 6) + (mi << 4) + (hi << 2) + reg;
                wv[wc][row] = v;
                wi[wc][row] = i;
            }
        }
    }
    __syncthreads();
    if (t < 128) {
        float v = wv[0][t];
        int i = wi[0][t];
        float ov = wv[1][t];
        int oi = wi[1][t];
        if (ov < v || (ov == v && oi < i)) { v = ov; i = oi; }
        pval[(size_t)(r0 + t) * 64 + kb] = v;
        pidx[(size_t)(r0 + t) * 64 + kb] = i;
    }
}

// ---------------------------------------------------------------------------
// full-res update for scales 7..10 (unchanged).
__global__ __launch_bounds__(256) void update_pool(
    const float* __restrict__ emb, const float* __restrict__ pval,
    const int* __restrict__ pidx, const float* __restrict__ rin,
    float* __restrict__ rout, const float* __restrict__ f,
    float* __restrict__ outp, float* __restrict__ parts,
    ushort* __restrict__ qh, ushort* __restrict__ ql,
    int pn, int gn, int pnn, int ks, int finalflag) {
    int blk = blockIdx.x;
    int b = blk >> 6, n16 = blk & 63;
    int t = threadIdx.x;
    int w = t >> 6, lane = t & 63;
    int n0 = n16 * 16;
    const float scale = (float)pn * (1.0f / 1024.0f);
    float s_lo = (n0 + 0.5f) * scale - 0.5f;
    if (s_lo < 0.f) s_lo = 0.f;
    int r_lo = (int)s_lo;
    float s_hi = (n0 + 15.5f) * scale - 0.5f;
    if (s_hi < 0.f) s_hi = 0.f;
    int r_hi = min((int)s_hi + 1, pn - 1);
    int cnt = r_hi - r_lo + 1;  // <= 18
    __shared__ int sidx[20];
    for (int ri = w; ri < cnt; ri += 4) {
        size_t rowg = (size_t)(b * pn + r_lo + ri) * 64;
        float v = (lane < ks) ? pval[rowg + lane] : FLT_MAX;
        int i = (lane < ks) ? pidx[rowg + lane] : 0x7fffffff;
#pragma unroll
        for (int d = 1; d < 64; d <<= 1) {
            float ov = __shfl_xor(v, d);
            int oi = __shfl_xor(i, d);
            if (ov < v || (ov == v && oi < i)) { v = ov; i = oi; }
        }
        if (lane == 0) sidx[ri] = i;
    }
    __syncthreads();
    __shared__ float4 rlds[16][64];  // 16 KB
    __shared__ float wred[4];
    int nsub = t >> 6;
    int c4 = t & 63;
    float sq = 0.f;
#pragma unroll
    for (int jj = 0; jj < 4; ++jj) {
        int j = nsub + 4 * jj;
        int n = n0 + j;
        float s = (n + 0.5f) * scale - 0.5f;
        if (s < 0.f) s = 0.f;
        int i0 = (int)s;
        float wgt = s - (float)i0;
        int i1 = min(i0 + 1, pn - 1);
        int k0 = sidx[i0 - r_lo];
        int k1 = sidx[i1 - r_lo];
        float4 e0 = ((const float4*)(emb + (size_t)k0 * CC))[c4];
        float4 e1 = ((const float4*)(emb + (size_t)k1 * CC))[c4];
        float wm = 1.f - wgt;
        float4 h = make_float4(wm * e0.x + wgt * e1.x, wm * e0.y + wgt * e1.y,
                               wm * e0.z + wgt * e1.z, wm * e0.w + wgt * e1.w);
        size_t o4 = ((size_t)b * NN + n) * 64 + c4;
        float4 rv0 = ((const float4*)rin)[o4];
        float4 rv = make_float4(rv0.x - h.x, rv0.y - h.y, rv0.z - h.z, rv0.w - h.w);
        if (!finalflag) {
            ((float4*)rout)[o4] = rv;
        } else {
            float4 fv = ((const float4*)f)[o4];
            ((float4*)outp)[o4] = make_float4(fv.x - rv.x, fv.y - rv.y,
                                              fv.z - rv.z, fv.w - rv.w);
        }
        sq += rv.x * rv.x + rv.y * rv.y + rv.z * rv.z + rv.w * rv.w;
        rlds[j][c4] = rv;
    }
    for (int off = 32; off > 0; off >>= 1) sq += __shfl_down(sq, off);
    if (lane == 0) wred[w] = sq;
    __syncthreads();
    if (t == 0) parts[blk] = wred[0] + wred[1] + wred[2] + wred[3];
    if (gn == 0) return;
    const float* rl = (const float*)rlds;  // [16][256]
    {
        float pr = 0.f;
        for (int j = 0; j < 16; ++j) {
            pr += rl[j * CC + t];
            if ((j & (gn - 1)) == (gn - 1)) {
                float mean = pr * (1.f / (float)gn);
                ushort H, L;
                split2(64.f * mean, H, L);
                size_t r = (size_t)b * pnn + (size_t)((n0 + j) / gn);
                qh[r * CC + t] = H;
                ql[r * CC + t] = L;
                pr = 0.f;
            }
        }
    }
}

// ---------------------------------------------------------------------------
__global__ void reduce_final(const float* __restrict__ parts, float* __restrict__ out) {
    __shared__ float red[256];
    int t = threadIdx.x;
    float s = 0.f;
    for (int i = t; i < SN * 512; i += 256) s += parts[i];
    red[t] = s;
    __syncthreads();
    for (int k = 128; k > 0; k >>= 1) {
        if (t < k) red[t] += red[t + k];
        __syncthreads();
    }
    if (t == 0) {
        float mean_sum = red[0] / (float)BNC;
        out[BNC] = 0.25f * mean_sum / (float)SN;
        out[BNC + 1] = mean_sum / (float)SN;
    }
}

// ---------------------------------------------------------------------------
extern "C" void kernel_launch(void* const* d_in, const int* in_sizes, int n_in,
                              void* d_out, int out_size, void* d_ws, size_t ws_size,
                              hipStream_t stream) {
    const float* f    = (const float*)d_in[0];
    const float* base = (const float*)d_in[1];
    const float* pw   = (const float*)d_in[2];
    const float* pb   = (const float*)d_in[3];
    float* out = (float*)d_out;

    float* emb   = (float*)d_ws;                    // K*C
    float* esq   = emb + (size_t)KK * CC;           // K
    float* pad0  = esq + KK;                        // C*C (layout pad)
    float* parts = pad0 + (size_t)CC * CC;          // SN*512
    float* pval  = parts + (size_t)SN * 512;        // RMAX*64 (large scales)
    float* p16   = pval + (size_t)RMAX * 64;        // B*64*C
    float* p16u  = p16 + (size_t)BB * 64 * CC;      // B*64*C -> persistent partials
    float* qf    = p16u + (size_t)BB * 64 * CC;     // 512*C
    float* resid = qf + (size_t)512 * CC;           // BNC
    int*   pidx  = (int*)(resid + BNC);             // RMAX*64 (large scales)
    ushort* eh = (ushort*)(pidx + (size_t)RMAX * 64);  // K*C
    ushort* el = eh + (size_t)KK * CC;              // K*C
    ushort* qh = el + (size_t)KK * CC;              // RMAX*C
    ushort* ql = qh + (size_t)RMAX * CC;            // RMAX*C
    // persistent small-scale partials carved from p16u (131072 floats):
    // rows = BB*(2^7-1) = 1016, x64 partials = 65024 <= 65536 each half.
    float* pvalS = p16u;
    int*   pidxS = (int*)(p16u + 65536);

    embed_prep<<<768, 256, 0, stream>>>(base, pw, pb, f, emb, eh, el, esq, p16);

    // scales 0..6: pooled-domain chain with persistent per-scale partials
    for (int sidx = 0; sidx <= 6; ++sidx) {
        int pn = 1 << sidx;
        int R = BB * pn;
        size_t rowoff = (size_t)BB * (pn - 1) * 64;
        dim3 grid(64, (R + 31) / 32);
        if (sidx == 0)
            dist_small<<<grid, 256, 0, stream>>>(p16, emb, esq, R, 64, 1, 64,
                                                 1.f / 1024.f, pvalS + rowoff, pidxS + rowoff);
        else
            dist_small<<<grid, 256, 0, stream>>>(qf, emb, esq, R, 1, pn, pn,
                                                 1.f, pvalS + rowoff, pidxS + rowoff);
        if (sidx < 6) {
            int pnn = pn << 1;
            combineQ<<<BB * pnn, 256, 0, stream>>>(pvalS, pidxS, p16, emb, qf, sidx, pnn);
        } else {
            bigpass<<<512, 256, 0, stream>>>(f, emb, pvalS, pidxS, resid, parts, qh, ql);
        }
    }

    // scales 7..10: full-res chain (scratch partials, consumed immediately)
    for (int sidx = 7; sidx < SN; ++sidx) {
        int pn = 1 << sidx;
        int R = BB * pn;
        dist_mfma<<<dim3(R / 128, 32), 256, 0, stream>>>(qh, ql, eh, el, esq, pval, pidx);
        int pnn = (sidx < SN - 1) ? (pn << 1) : 0;
        int gn = pnn ? (NN / pnn) : 0;
        update_pool<<<BB * 64, 256, 0, stream>>>(emb, pval, pidx, resid, resid, f, out,
                                                 parts + (size_t)sidx * 512,
                                                 qh, ql, pn, gn, pnn, 32,
                                                 (sidx == SN - 1) ? 1 : 0);
    }
    reduce_final<<<1, 256, 0, stream>>>(parts, out);
}

// Round 15
// 550.745 us; speedup vs baseline: 1.1513x; 1.1513x over previous
//
#include <hip/hip_runtime.h>
#include <cfloat>

#define BB 8
#define NN 1024
#define CC 256
#define KK 4096
#define SN 11
#define BNC (BB*NN*CC)
#define RMAX 8192

typedef __attribute__((ext_vector_type(8))) _Float16 half8;
typedef __attribute__((ext_vector_type(4))) float f32x4;

__device__ __forceinline__ void split2(float v, ushort& h, ushort& l) {
    union { _Float16 f; ushort u; } a, b;
    a.f = (_Float16)v;
    b.f = (_Float16)(v - (float)a.f);
    h = a.u; l = b.u;
}

// ---------------------------------------------------------------------------
// merged: blocks 0-255 embed (pw read transposed directly); 256-767 init_pool16
__global__ __launch_bounds__(256) void embed_prep(
    const float* __restrict__ base, const float* __restrict__ pw,
    const float* __restrict__ pb, const float* __restrict__ f,
    float* __restrict__ emb, ushort* __restrict__ eh, ushort* __restrict__ el,
    float* __restrict__ esq, float* __restrict__ p16) {
    int blk = blockIdx.x;
    int t = threadIdx.x;
    if (blk >= 256) {
        int bb = blk - 256;
        int c4 = t & 63;
        const float4* src = (const float4*)(f + (size_t)bb * 16 * CC) + c4;
        float4 s = make_float4(0.f, 0.f, 0.f, 0.f);
#pragma unroll
        for (int j = 0; j < 16; ++j) {
            float4 v = src[(size_t)j * 64];
            s.x += v.x; s.y += v.y; s.z += v.z; s.w += v.w;
        }
        ((float4*)(p16 + (size_t)bb * CC))[c4] = s;
        return;
    }
    __shared__ float bs[16][CC];
    __shared__ float wpart[16][4];
    int k0 = blk * 16;
    int w = t >> 6, lane = t & 63;
    for (int i = t; i < 16 * CC; i += 256) bs[i >> 8][i & 255] = base[k0 * CC + i];
    __syncthreads();
    float acc[16];
#pragma unroll
    for (int m = 0; m < 16; ++m) acc[m] = 0.f;
    for (int j = 0; j < CC; ++j) {
        float wv = pw[t * CC + j];
#pragma unroll
        for (int m = 0; m < 16; ++m) acc[m] += bs[m][j] * wv;
    }
    float bias = pb[t];
#pragma unroll
    for (int m = 0; m < 16; ++m) {
        float v = acc[m] + bias;
        int o = (k0 + m) * CC + t;
        emb[o] = v;
        ushort h, l;
        split2(64.f * v, h, l);
        eh[o] = h; el[o] = l;
        float sq = v * v;
#pragma unroll
        for (int d = 1; d < 64; d <<= 1) sq += __shfl_xor(sq, d);
        if (lane == 0) wpart[m][w] = sq;
    }
    __syncthreads();
    if (t < 16) esq[k0 + t] = wpart[t][0] + wpart[t][1] + wpart[t][2] + wpart[t][3];
}

// ---------------------------------------------------------------------------
// exact f32 distance+argmin for small scales (R <= 512), with fused pooling.
// srow = row stride of src in 256-float rows (64 for p16 pyramid, pn for qf).
__global__ __launch_bounds__(256, 4) void dist_small(
    const float* __restrict__ src, const float* __restrict__ emb,
    const float* __restrict__ esq, int R, int g16, int pn, int srow, float inv,
    float* __restrict__ pval, int* __restrict__ pidx) {
    __shared__ float qs[32][CC];
    __shared__ float es[64][33];
    int t = threadIdx.x;
    int ws = t >> 6, j = t & 63;
    int k0 = blockIdx.x * 64;
    int r0c = blockIdx.y * 32;
    {
        int row = t >> 3;
        int f4b = (t & 7) * 8;
        int gr = r0c + row;
        float4 a4[8];
#pragma unroll
        for (int ii = 0; ii < 8; ++ii) a4[ii] = make_float4(0.f, 0.f, 0.f, 0.f);
        if (gr < R) {
            int b = gr / pn, p = gr - b * pn;
            const float4* sp = (const float4*)(src + ((size_t)b * srow + (size_t)p * g16) * CC) + f4b;
            for (int i = 0; i < g16; ++i) {
#pragma unroll
                for (int ii = 0; ii < 8; ++ii) {
                    float4 v = sp[ii];
                    a4[ii].x += v.x; a4[ii].y += v.y; a4[ii].z += v.z; a4[ii].w += v.w;
                }
                sp += 64;
            }
        }
#pragma unroll
        for (int ii = 0; ii < 8; ++ii) {
            a4[ii].x *= inv; a4[ii].y *= inv; a4[ii].z *= inv; a4[ii].w *= inv;
            *(float4*)&qs[row][(f4b + ii) * 4] = a4[ii];
        }
    }
    float acc[8];
#pragma unroll
    for (int ri = 0; ri < 8; ++ri) acc[ri] = 0.f;
    for (int ck = 0; ck < 8; ++ck) {
        __syncthreads();
        {
            int code = t >> 2, cb = (t & 3) * 8;
            float4 v0 = *(const float4*)&emb[(size_t)(k0 + code) * CC + ck * 32 + cb];
            float4 v1 = *(const float4*)&emb[(size_t)(k0 + code) * CC + ck * 32 + cb + 4];
            es[code][cb + 0] = v0.x; es[code][cb + 1] = v0.y;
            es[code][cb + 2] = v0.z; es[code][cb + 3] = v0.w;
            es[code][cb + 4] = v1.x; es[code][cb + 5] = v1.y;
            es[code][cb + 6] = v1.z; es[code][cb + 7] = v1.w;
        }
        __syncthreads();
        for (int c = 0; c < 32; ++c) {
            float ev = es[j][c];
#pragma unroll
            for (int ri = 0; ri < 8; ++ri)
                acc[ri] += qs[ws + 4 * ri][ck * 32 + c] * ev;
        }
    }
    float esv = esq[k0 + j];
#pragma unroll
    for (int ri = 0; ri < 8; ++ri) {
        int r = r0c + ws + 4 * ri;
        if (r >= R) continue;
        float v = esv - 2.f * acc[ri];
        int bi = k0 + j;
#pragma unroll
        for (int d = 1; d < 64; d <<= 1) {
            float ov = __shfl_xor(v, d);
            int oi = __shfl_xor(bi, d);
            if (ov < v || (ov == v && oi < bi)) { v = ov; bi = oi; }
        }
        if (j == 0) {
            pval[(size_t)r * 64 + blockIdx.x] = v;
            pidx[(size_t)r * 64 + blockIdx.x] = bi;
        }
    }
}

// ---------------------------------------------------------------------------
// MFMA distance, pn >= 128 (2-phase-ceiling version).
// f16 2-split, 3 passes; 4 waves 2x2; wave tile 64x64; block 128x128; BK=64
// single-buffer LDS staged via global_load_lds with XOR-(row&7) pre-swizzled
// global source (free 2-way conflicts).
__global__ __launch_bounds__(256, 2) void dist_mfma(
    const ushort* __restrict__ qh, const ushort* __restrict__ ql,
    const ushort* __restrict__ eh, const ushort* __restrict__ el,
    const float* __restrict__ esq,
    float* __restrict__ pval, int* __restrict__ pidx) {
    __shared__ ushort tiles[4096 * 8];  // 64 KB
    __shared__ float wv[2][128];
    __shared__ int wi[2][128];
    int t = threadIdx.x;
    int w = t >> 6, lane = t & 63;
    int l15 = lane & 15, hi = lane >> 4;
    int wr = w >> 1, wc = w & 1;
    int r0 = blockIdx.x * 128;
    int kb = blockIdx.y;
    int k0 = kb * 128;

    f32x4 acc[4][4];
#pragma unroll
    for (int mi = 0; mi < 4; ++mi)
#pragma unroll
        for (int ni = 0; ni < 4; ++ni) acc[mi][ni] = (f32x4){0.f, 0.f, 0.f, 0.f};

    for (int ck = 0; ck < 4; ++ck) {
        __syncthreads();
#pragma unroll
        for (int it = 0; it < 16; ++it) {
            int s = it * 256 + t;
            const ushort* g;
            if (s < 2048) {
                int a = s >> 10;
                int rem = s & 1023;
                int row = rem >> 3, sr = rem & 7;
                int c = (ck << 6) + ((sr ^ (row & 7)) << 3);
                g = (a ? ql : qh) + (size_t)(r0 + row) * CC + c;
            } else {
                int s2 = s - 2048;
                int b = s2 >> 10;
                int rem = s2 & 1023;
                int kcol = rem >> 3, sr = rem & 7;
                int c = (ck << 6) + ((sr ^ (kcol & 7)) << 3);
                g = (b ? el : eh) + (size_t)(k0 + kcol) * CC + c;
            }
            ushort* lb = &tiles[(size_t)(it * 256 + (w << 6)) * 8];
            __builtin_amdgcn_global_load_lds(
                (const __attribute__((address_space(1))) unsigned int*)g,
                (__attribute__((address_space(3))) unsigned int*)lb, 16, 0, 0);
        }
        __syncthreads();

#pragma unroll
        for (int kk = 0; kk < 2; ++kk) {
            int cs = (kk << 2) + hi;
            half8 bf0[4], bf1[4], af[4];
#pragma unroll
            for (int ni = 0; ni < 4; ++ni) {
                int kcol = (wc << 6) + (ni << 4) + l15;
                int sb = 2048 + (kcol << 3) + (cs ^ (kcol & 7));
                bf0[ni] = *(const half8*)&tiles[sb * 8];
                bf1[ni] = *(const half8*)&tiles[(sb + 1024) * 8];
            }
#pragma unroll
            for (int mi = 0; mi < 4; ++mi) {
                int row = (wr << 6) + (mi << 4) + l15;
                af[mi] = *(const half8*)&tiles[((row << 3) + (cs ^ (row & 7))) * 8];
            }
#pragma unroll
            for (int mi = 0; mi < 4; ++mi)
#pragma unroll
                for (int ni = 0; ni < 4; ++ni)
                    acc[mi][ni] = __builtin_amdgcn_mfma_f32_16x16x32_f16(af[mi], bf0[ni], acc[mi][ni], 0, 0, 0);
#pragma unroll
            for (int mi = 0; mi < 4; ++mi)
#pragma unroll
                for (int ni = 0; ni < 4; ++ni)
                    acc[mi][ni] = __builtin_amdgcn_mfma_f32_16x16x32_f16(af[mi], bf1[ni], acc[mi][ni], 0, 0, 0);
#pragma unroll
            for (int mi = 0; mi < 4; ++mi) {
                int row = (wr << 6) + (mi << 4) + l15;
                af[mi] = *(const half8*)&tiles[(1024 + (row << 3) + (cs ^ (row & 7))) * 8];
            }
#pragma unroll
            for (int mi = 0; mi < 4; ++mi)
#pragma unroll
                for (int ni = 0; ni < 4; ++ni)
                    acc[mi][ni] = __builtin_amdgcn_mfma_f32_16x16x32_f16(af[mi], bf0[ni], acc[mi][ni], 0, 0, 0);
        }
    }

    int cbase = k0 + (wc << 6) + l15;
    float es4[4];
#pragma unroll
    for (int ni = 0; ni < 4; ++ni) es4[ni] = 4096.f * esq[cbase + ni * 16];
#pragma unroll
    for (int mi = 0; mi < 4; ++mi) {
#pragma unroll
        for (int reg = 0; reg < 4; ++reg) {
            float v = es4[0] - 2.f * acc[mi][0][reg];
            int i = cbase;
#pragma unroll
            for (int ni = 1; ni < 4; ++ni) {
                float v1 = es4[ni] - 2.f * acc[mi][ni][reg];
                if (v1 < v) { v = v1; i = cbase + ni * 16; }
            }
#pragma unroll
            for (int d = 1; d < 16; d <<= 1) {
                float ov = __shfl_xor(v, d);
                int oi = __shfl_xor(i, d);
                if (ov < v || (ov == v && oi < i)) { v = ov; i = oi; }
            }
            if (l15 == 0) {
                int row = (wr << 6) + (mi << 4) + (hi << 2) + reg;
                wv[wc][row] = v;
                wi[wc][row] = i;
            }
        }
    }
    __syncthreads();
    if (t < 128) {
        float v = wv[0][t];
        int i = wi[0][t];
        float ov = wv[1][t];
        int oi = wi[1][t];
        if (ov < v || (ov == v && oi < i)) { v = ov; i = oi; }
        pval[(size_t)(r0 + t) * 64 + kb] = v;
        pidx[(size_t)(r0 + t) * 64 + kb] = i;
    }
}

// ---------------------------------------------------------------------------
// fused: per-row argmin combine + gather + interp + residual update (float4) +
// loss partial + NEXT-scale pooling (bit-identical scalar order via LDS).
__global__ __launch_bounds__(256) void update_pool(
    const float* __restrict__ emb, const float* __restrict__ pval,
    const int* __restrict__ pidx, const float* __restrict__ rin,
    float* __restrict__ rout, const float* __restrict__ f,
    float* __restrict__ outp, float* __restrict__ parts,
    ushort* __restrict__ qh, ushort* __restrict__ ql,
    float* __restrict__ qf, float* __restrict__ p16u,
    int pn, int gn, int pnn, int ks, int finalflag) {
    int blk = blockIdx.x;
    int b = blk >> 6, n16 = blk & 63;
    int t = threadIdx.x;
    int w = t >> 6, lane = t & 63;
    int n0 = n16 * 16;
    const float scale = (float)pn * (1.0f / 1024.0f);
    float s_lo = (n0 + 0.5f) * scale - 0.5f;
    if (s_lo < 0.f) s_lo = 0.f;
    int r_lo = (int)s_lo;
    float s_hi = (n0 + 15.5f) * scale - 0.5f;
    if (s_hi < 0.f) s_hi = 0.f;
    int r_hi = min((int)s_hi + 1, pn - 1);
    int cnt = r_hi - r_lo + 1;  // <= 18
    __shared__ int sidx[20];
    for (int ri = w; ri < cnt; ri += 4) {
        size_t rowg = (size_t)(b * pn + r_lo + ri) * 64;
        float v = (lane < ks) ? pval[rowg + lane] : FLT_MAX;
        int i = (lane < ks) ? pidx[rowg + lane] : 0x7fffffff;
#pragma unroll
        for (int d = 1; d < 64; d <<= 1) {
            float ov = __shfl_xor(v, d);
            int oi = __shfl_xor(i, d);
            if (ov < v || (ov == v && oi < i)) { v = ov; i = oi; }
        }
        if (lane == 0) sidx[ri] = i;
    }
    __syncthreads();
    __shared__ float4 rlds[16][64];  // 16 KB
    __shared__ float wred[4];
    int nsub = t >> 6;
    int c4 = t & 63;
    float sq = 0.f;
#pragma unroll
    for (int jj = 0; jj < 4; ++jj) {
        int j = nsub + 4 * jj;
        int n = n0 + j;
        float s = (n + 0.5f) * scale - 0.5f;
        if (s < 0.f) s = 0.f;
        int i0 = (int)s;
        float wgt = s - (float)i0;
        int i1 = min(i0 + 1, pn - 1);
        int k0 = sidx[i0 - r_lo];
        int k1 = sidx[i1 - r_lo];
        float4 e0 = ((const float4*)(emb + (size_t)k0 * CC))[c4];
        float4 e1 = ((const float4*)(emb + (size_t)k1 * CC))[c4];
        float wm = 1.f - wgt;
        float4 h = make_float4(wm * e0.x + wgt * e1.x, wm * e0.y + wgt * e1.y,
                               wm * e0.z + wgt * e1.z, wm * e0.w + wgt * e1.w);
        size_t o4 = ((size_t)b * NN + n) * 64 + c4;
        float4 rv0 = ((const float4*)rin)[o4];
        float4 rv = make_float4(rv0.x - h.x, rv0.y - h.y, rv0.z - h.z, rv0.w - h.w);
        if (!finalflag) {
            ((float4*)rout)[o4] = rv;
        } else {
            float4 fv = ((const float4*)f)[o4];
            ((float4*)outp)[o4] = make_float4(fv.x - rv.x, fv.y - rv.y,
                                              fv.z - rv.z, fv.w - rv.w);
        }
        sq += rv.x * rv.x + rv.y * rv.y + rv.z * rv.z + rv.w * rv.w;
        rlds[j][c4] = rv;
    }
    for (int off = 32; off > 0; off >>= 1) sq += __shfl_down(sq, off);
    if (lane == 0) wred[w] = sq;
    __syncthreads();
    if (t == 0) parts[blk] = wred[0] + wred[1] + wred[2] + wred[3];
    if (gn == 0) return;
    const float* rl = (const float*)rlds;  // [16][256]
    if (gn < 16) {
        float pr = 0.f;
        for (int j = 0; j < 16; ++j) {
            pr += rl[j * CC + t];
            if ((j & (gn - 1)) == (gn - 1)) {
                float mean = pr * (1.f / (float)gn);
                ushort H, L;
                split2(64.f * mean, H, L);
                size_t r = (size_t)b * pnn + (size_t)((n0 + j) / gn);
                qh[r * CC + t] = H;
                ql[r * CC + t] = L;
                pr = 0.f;
            }
        }
    } else {
        float pr = 0.f;
        for (int j = 0; j < 16; ++j) pr += rl[j * CC + t];
        if (gn == 16) qf[(size_t)blk * CC + t] = pr * (1.f / 16.f);
        else p16u[(size_t)blk * CC + t] = pr;
    }
}

// ---------------------------------------------------------------------------
__global__ void reduce_final(const float* __restrict__ parts, float* __restrict__ out) {
    __shared__ float red[256];
    int t = threadIdx.x;
    float s = 0.f;
    for (int i = t; i < SN * 512; i += 256) s += parts[i];
    red[t] = s;
    __syncthreads();
    for (int k = 128; k > 0; k >>= 1) {
        if (t < k) red[t] += red[t + k];
        __syncthreads();
    }
    if (t == 0) {
        float mean_sum = red[0] / (float)BNC;
        out[BNC] = 0.25f * mean_sum / (float)SN;
        out[BNC + 1] = mean_sum / (float)SN;
    }
}

// ---------------------------------------------------------------------------
extern "C" void kernel_launch(void* const* d_in, const int* in_sizes, int n_in,
                              void* d_out, int out_size, void* d_ws, size_t ws_size,
                              hipStream_t stream) {
    const float* f    = (const float*)d_in[0];
    const float* base = (const float*)d_in[1];
    const float* pw   = (const float*)d_in[2];
    const float* pb   = (const float*)d_in[3];
    float* out = (float*)d_out;

    float* emb   = (float*)d_ws;                    // K*C
    float* esq   = emb + (size_t)KK * CC;           // K
    float* pad0  = esq + KK;                        // C*C (layout pad)
    float* parts = pad0 + (size_t)CC * CC;          // SN*512
    float* pval  = parts + (size_t)SN * 512;        // RMAX*64
    float* p16   = pval + (size_t)RMAX * 64;        // B*64*C
    float* p16u  = p16 + (size_t)BB * 64 * CC;      // B*64*C
    float* qf    = p16u + (size_t)BB * 64 * CC;     // 512*C
    float* resid = qf + (size_t)512 * CC;           // BNC
    int*   pidx  = (int*)(resid + BNC);             // RMAX*64
    ushort* eh = (ushort*)(pidx + (size_t)RMAX * 64);  // K*C
    ushort* el = eh + (size_t)KK * CC;              // K*C
    ushort* qh = el + (size_t)KK * CC;              // RMAX*C
    ushort* ql = qh + (size_t)RMAX * CC;            // RMAX*C

    embed_prep<<<768, 256, 0, stream>>>(base, pw, pb, f, emb, eh, el, esq, p16);

    for (int sidx = 0; sidx < SN; ++sidx) {
        int pn = 1 << sidx;
        int R = BB * pn;
        int ks;
        if (pn <= 64) {
            const float* src;
            float inv;
            int g16;
            if (pn == 64)      { src = qf;   g16 = 1;       inv = 1.f; }
            else if (pn == 1)  { src = p16;  g16 = 64;      inv = 1.f / 1024.f; }
            else               { src = p16u; g16 = 64 / pn; inv = 1.f / (16.f * (64 / pn)); }
            dim3 grid(64, (R + 31) / 32);
            dist_small<<<grid, 256, 0, stream>>>(src, emb, esq, R, g16, pn, 64, inv, pval, pidx);
            ks = 64;
        } else {
            dist_mfma<<<dim3(R / 128, 32), 256, 0, stream>>>(qh, ql, eh, el, esq, pval, pidx);
            ks = 32;
        }
        int pnn = (sidx < SN - 1) ? (pn << 1) : 0;
        int gn = pnn ? (NN / pnn) : 0;
        const float* rin = (sidx == 0) ? f : resid;
        update_pool<<<BB * 64, 256, 0, stream>>>(emb, pval, pidx, rin, resid, f, out,
                                                 parts + (size_t)sidx * 512,
                                                 qh, ql, qf, p16u, pn, gn, pnn, ks,
                                                 (sidx == SN - 1) ? 1 : 0);
    }
    reduce_final<<<1, 256, 0, stream>>>(parts, out);
}